// Round 4
// baseline (348.396 us; speedup 1.0000x reference)
//
#include <hip/hip_runtime.h>
#include <hip/hip_bf16.h>
#include <stdint.h>

#define NB 4096
#define ND 256
#define NC 32000

typedef __bf16 bf16x8 __attribute__((ext_vector_type(8)));
typedef float  f32x4  __attribute__((ext_vector_type(4)));

__device__ __forceinline__ unsigned short f32_to_bf16(float f) {
  union { float f; uint32_t u; } v; v.f = f;
  uint32_t r = v.u + 0x7fffu + ((v.u >> 16) & 1u);
  return (unsigned short)(r >> 16);
}

// Cast inputs/V to bf16 in workspace; zero rowsum + loss accumulator.
__global__ void prep_kernel(const float* __restrict__ inA,
                            const float* __restrict__ inV,
                            unsigned short* __restrict__ outA,
                            unsigned short* __restrict__ outV,
                            float* __restrict__ rowsum,
                            float* __restrict__ loss) {
  int gid = blockIdx.x * blockDim.x + threadIdx.x;
  int stride = gridDim.x * blockDim.x;
  if (gid == 0) *loss = 0.f;
  for (int i = gid; i < NB; i += stride) rowsum[i] = 0.f;
  const int nA4 = NB * ND / 4;   // 262144
  const int nV4 = NC * ND / 4;   // 2048000
  for (int i = gid; i < nA4 + nV4; i += stride) {
    float4 v = (i < nA4) ? ((const float4*)inA)[i]
                         : ((const float4*)inV)[i - nA4];
    ushort4 o;
    o.x = f32_to_bf16(v.x);
    o.y = f32_to_bf16(v.y);
    o.z = f32_to_bf16(v.z);
    o.w = f32_to_bf16(v.w);
    if (i < nA4) ((ushort4*)outA)[i] = o;
    else         ((ushort4*)outV)[i - nA4] = o;
  }
}

// Barrier-free, LDS-free GEMM: 128x128 tile, 4 waves (2x2), wave = 64x64 via
// 4x4 mfma 16x16x32 frags, SWAPPED operands: mfma(Vfrag, Afrag, acc) so the
// C-fragment lands transposed -- each lane's 4 acc regs = 4 consecutive
// output COLS of one row -> direct float4 stores, no LDS transpose.
// XCD swizzle: col-tiles padded 250->256, each XCD owns a 32-col-tile chunk
// (V slice 2MB fits L2), col-fast within chunk -> contiguous DRAM write
// spans + V reuse in L2.
__global__ void __launch_bounds__(256, 2)
gemm_expsum_kernel(const unsigned short* __restrict__ A,
                   const unsigned short* __restrict__ V,
                   float* __restrict__ out,     // d_out + 1
                   float* __restrict__ rowsum) {
  const int b = blockIdx.x;
  const int xcd = b & 7;
  const int s = b >> 3;               // 0..1023 per XCD
  const int colt = (xcd << 5) + (s & 31);   // 32 col-tiles per XCD, col-fast
  const int rowt = s >> 5;                  // 0..31
  if (colt >= NC / 128) return;             // padded tail (colt 250..255)
  const int brow = rowt << 7;
  const int bcol = colt << 7;

  const int tid  = threadIdx.x;
  const int lane = tid & 63;
  const int wave = tid >> 6;
  const int wr   = wave >> 1;
  const int wc   = wave & 1;
  const int c16  = lane & 15;
  const int kq   = lane >> 4;      // 0..3

  const __bf16* Ab = (const __bf16*)A;
  const __bf16* Vb = (const __bf16*)V;
  // lane's fragment base: row (c16), k-chunk kq*8
  const __bf16* aBase = Ab + (size_t)(brow + wr * 64 + c16) * ND + kq * 8;
  const __bf16* bBase = Vb + (size_t)(bcol + wc * 64 + c16) * ND + kq * 8;

  f32x4 acc[4][4];   // acc[c][r]: c = V-frag (out cols), r = A-frag (out rows)
#pragma unroll
  for (int c = 0; c < 4; ++c)
#pragma unroll
    for (int r = 0; r < 4; ++r)
      acc[c][r] = (f32x4){0.f, 0.f, 0.f, 0.f};

  bf16x8 a0[4], b0[4], a1[4], b1[4];

#define LOADF(AF, BF, KT)                                                     \
  do {                                                                        \
    _Pragma("unroll")                                                         \
    for (int m = 0; m < 4; ++m)                                               \
      AF[m] = *(const bf16x8*)(aBase + (size_t)m * 16 * ND + (KT) * 32);      \
    _Pragma("unroll")                                                         \
    for (int n = 0; n < 4; ++n)                                               \
      BF[n] = *(const bf16x8*)(bBase + (size_t)n * 16 * ND + (KT) * 32);      \
  } while (0)

  // swapped operand order: D[v_row][a_row] => lane reg = consecutive out cols
#define MFMAALL(AF, BF)                                                       \
  do {                                                                        \
    _Pragma("unroll")                                                         \
    for (int c = 0; c < 4; ++c)                                               \
      _Pragma("unroll")                                                       \
      for (int r = 0; r < 4; ++r)                                             \
        acc[c][r] = __builtin_amdgcn_mfma_f32_16x16x32_bf16(BF[c], AF[r],     \
                                                            acc[c][r], 0, 0, 0); \
  } while (0)

  LOADF(a0, b0, 0);
#pragma unroll
  for (int kt = 0; kt < 8; kt += 2) {
    if (kt + 1 < 8) LOADF(a1, b1, kt + 1);
    MFMAALL(a0, b0);
    if (kt + 2 < 8) LOADF(a0, b0, kt + 2);
    MFMAALL(a1, b1);
  }

  // Epilogue: direct float4 stores (no LDS), fused exp-rowsum.
  // acc[c][r] regs q=0..3 map to out[brow+wr*64+r*16+c16][bcol+wc*64+c*16+kq*4+q]
#pragma unroll
  for (int r = 0; r < 4; ++r) {
    const int grow = brow + wr * 64 + r * 16 + c16;
    float* prow = out + (size_t)grow * NC + (bcol + wc * 64 + kq * 4);
    float sum = 0.f;
#pragma unroll
    for (int c = 0; c < 4; ++c) {
      f32x4 v = acc[c][r];
      *(f32x4*)(prow + c * 16) = v;
      sum += __expf(v[0]) + __expf(v[1]) + __expf(v[2]) + __expf(v[3]);
    }
    // reduce over kq groups (lane = kq*16 + c16): xor 16, 32
    sum += __shfl_xor(sum, 16);
    sum += __shfl_xor(sum, 32);
    if (lane < 16) atomicAdd(&rowsum[grow], sum);
  }
#undef LOADF
#undef MFMAALL
}

// loss = mean_i( log(rowsum[i]) - out[i, targets[i]] )
__global__ void finalize_kernel(const float* __restrict__ rowsum,
                                const float* __restrict__ out,  // d_out + 1
                                const int* __restrict__ targets,
                                float* __restrict__ loss) {
  int i = blockIdx.x * blockDim.x + threadIdx.x;
  float li = 0.f;
  if (i < NB) {
    float lse = logf(rowsum[i]);
    float xt  = out[(size_t)i * NC + targets[i]];
    li = lse - xt;
  }
#pragma unroll
  for (int o = 32; o > 0; o >>= 1) li += __shfl_down(li, o);
  __shared__ float wsum[4];
  int lane = threadIdx.x & 63, wv = threadIdx.x >> 6;
  if (lane == 0) wsum[wv] = li;
  __syncthreads();
  if (threadIdx.x == 0) {
    float s = wsum[0] + wsum[1] + wsum[2] + wsum[3];
    atomicAdd(loss, s * (1.0f / NB));
  }
}

extern "C" void kernel_launch(void* const* d_in, const int* in_sizes, int n_in,
                              void* d_out, int out_size, void* d_ws, size_t ws_size,
                              hipStream_t stream) {
  const float* inputs  = (const float*)d_in[0];
  const int*   targets = (const int*)d_in[1];
  // d_in[2] indexs, d_in[3] label_to_pairs, d_in[4] all_label_to_clusterid: unused (W_MS = 0)
  const float* V       = (const float*)d_in[5];

  float* loss    = (float*)d_out;          // output 0: scalar loss
  float* outputs = (float*)d_out + 1;      // output 1: [4096][32000]

  char* ws = (char*)d_ws;
  unsigned short* Abf = (unsigned short*)ws;                              // 2 MB
  unsigned short* Vbf = (unsigned short*)(ws + (size_t)NB * ND * 2);      // 16.4 MB
  float* rowsum = (float*)(ws + (size_t)NB * ND * 2 + (size_t)NC * ND * 2);

  hipLaunchKernelGGL(prep_kernel, dim3(2048), dim3(256), 0, stream,
                     inputs, V, Abf, Vbf, rowsum, loss);
  // grid: 8 XCDs x 1024 (32 col-tiles x 32 row-tiles), col-tiles padded to 256
  hipLaunchKernelGGL(gemm_expsum_kernel, dim3(8 * 1024), dim3(256), 0, stream,
                     Abf, Vbf, outputs, rowsum);
  hipLaunchKernelGGL(finalize_kernel, dim3(NB / 256), dim3(256), 0, stream,
                     rowsum, outputs, targets, loss);
}

// Round 5
// 343.273 us; speedup vs baseline: 1.0149x; 1.0149x over previous
//
#include <hip/hip_runtime.h>
#include <hip/hip_bf16.h>
#include <stdint.h>

#define NB 4096
#define ND 256
#define NC 32000
#define NCT (NC / 128)   // 250 col-tiles

typedef __bf16 bf16x8 __attribute__((ext_vector_type(8)));
typedef float  f32x4  __attribute__((ext_vector_type(4)));

__device__ __forceinline__ unsigned short f32_to_bf16(float f) {
  union { float f; uint32_t u; } v; v.f = f;
  uint32_t r = v.u + 0x7fffu + ((v.u >> 16) & 1u);
  return (unsigned short)(r >> 16);
}

// Cast inputs/V to bf16 in workspace; zero loss accumulator.
__global__ void prep_kernel(const float* __restrict__ inA,
                            const float* __restrict__ inV,
                            unsigned short* __restrict__ outA,
                            unsigned short* __restrict__ outV,
                            float* __restrict__ loss) {
  int gid = blockIdx.x * blockDim.x + threadIdx.x;
  int stride = gridDim.x * blockDim.x;
  if (gid == 0) *loss = 0.f;
  const int nA4 = NB * ND / 4;   // 262144
  const int nV4 = NC * ND / 4;   // 2048000
  for (int i = gid; i < nA4 + nV4; i += stride) {
    float4 v = (i < nA4) ? ((const float4*)inA)[i]
                         : ((const float4*)inV)[i - nA4];
    ushort4 o;
    o.x = f32_to_bf16(v.x);
    o.y = f32_to_bf16(v.y);
    o.z = f32_to_bf16(v.z);
    o.w = f32_to_bf16(v.w);
    if (i < nA4) ((ushort4*)outA)[i] = o;
    else         ((ushort4*)outV)[i - nA4] = o;
  }
}

// Barrier-free (in K-loop), LDS-free GEMM: 128x128 tile, 4 waves (2x2),
// wave = 64x64 via 4x4 mfma 16x16x32 frags, SWAPPED operands so each lane's
// acc regs = 4 consecutive output cols of one row -> direct float4 stores.
// Epilogue exp-rowsums go to a per-col-tile partial array via ONE plain
// 512B store per block (no global atomics -- R4's wall was ~2M device-scope
// atomicAdds hot-lining a 16KB rowsum array).
__global__ void __launch_bounds__(256, 2)
gemm_expsum_kernel(const unsigned short* __restrict__ A,
                   const unsigned short* __restrict__ V,
                   float* __restrict__ out,       // d_out + 1
                   float* __restrict__ partial) { // [NCT][NB]
  __shared__ float red[2][128];

  const int b = blockIdx.x;
  const int xcd = b & 7;
  const int s = b >> 3;               // 0..1023 per XCD
  const int colt = (xcd << 5) + (s & 31);   // 32 col-tiles per XCD, col-fast
  const int rowt = s >> 5;                  // 0..31
  if (colt >= NCT) return;                  // padded tail (colt 250..255)
  const int brow = rowt << 7;
  const int bcol = colt << 7;

  const int tid  = threadIdx.x;
  const int lane = tid & 63;
  const int wave = tid >> 6;
  const int wr   = wave >> 1;
  const int wc   = wave & 1;
  const int c16  = lane & 15;
  const int kq   = lane >> 4;      // 0..3

  const __bf16* Ab = (const __bf16*)A;
  const __bf16* Vb = (const __bf16*)V;
  const __bf16* aBase = Ab + (size_t)(brow + wr * 64 + c16) * ND + kq * 8;
  const __bf16* bBase = Vb + (size_t)(bcol + wc * 64 + c16) * ND + kq * 8;

  f32x4 acc[4][4];   // acc[c][r]: c = V-frag (out cols), r = A-frag (out rows)
#pragma unroll
  for (int c = 0; c < 4; ++c)
#pragma unroll
    for (int r = 0; r < 4; ++r)
      acc[c][r] = (f32x4){0.f, 0.f, 0.f, 0.f};

  bf16x8 a0[4], b0[4], a1[4], b1[4];

#define LOADF(AF, BF, KT)                                                     \
  do {                                                                        \
    _Pragma("unroll")                                                         \
    for (int m = 0; m < 4; ++m)                                               \
      AF[m] = *(const bf16x8*)(aBase + (size_t)m * 16 * ND + (KT) * 32);      \
    _Pragma("unroll")                                                         \
    for (int n = 0; n < 4; ++n)                                               \
      BF[n] = *(const bf16x8*)(bBase + (size_t)n * 16 * ND + (KT) * 32);      \
  } while (0)

#define MFMAALL(AF, BF)                                                       \
  do {                                                                        \
    _Pragma("unroll")                                                         \
    for (int c = 0; c < 4; ++c)                                               \
      _Pragma("unroll")                                                       \
      for (int r = 0; r < 4; ++r)                                             \
        acc[c][r] = __builtin_amdgcn_mfma_f32_16x16x32_bf16(BF[c], AF[r],     \
                                                            acc[c][r], 0, 0, 0); \
  } while (0)

  LOADF(a0, b0, 0);
#pragma unroll
  for (int kt = 0; kt < 8; kt += 2) {
    if (kt + 1 < 8) LOADF(a1, b1, kt + 1);
    MFMAALL(a0, b0);
    if (kt + 2 < 8) LOADF(a0, b0, kt + 2);
    MFMAALL(a1, b1);
  }

  // Epilogue: direct float4 stores + exp-rowsum into LDS (no atomics).
#pragma unroll
  for (int r = 0; r < 4; ++r) {
    const int grow = brow + wr * 64 + r * 16 + c16;
    float* prow = out + (size_t)grow * NC + (bcol + wc * 64 + kq * 4);
    float sum = 0.f;
#pragma unroll
    for (int c = 0; c < 4; ++c) {
      f32x4 v = acc[c][r];
      *(f32x4*)(prow + c * 16) = v;
      sum += __expf(v[0]) + __expf(v[1]) + __expf(v[2]) + __expf(v[3]);
    }
    // reduce over kq groups (lane = kq*16 + c16)
    sum += __shfl_xor(sum, 16);
    sum += __shfl_xor(sum, 32);
    if (lane < 16) red[wc][wr * 64 + r * 16 + c16] = sum;
  }
  __syncthreads();
  if (tid < 128)
    partial[(size_t)colt * NB + brow + tid] = red[0][tid] + red[1][tid];
#undef LOADF
#undef MFMAALL
}

// loss = mean_r( log(sum_c partial[c][r]) - out[r, targets[r]] )
__global__ void finalize_kernel(const float* __restrict__ partial,
                                const float* __restrict__ out,  // d_out + 1
                                const int* __restrict__ targets,
                                float* __restrict__ loss) {
  int r = blockIdx.x * blockDim.x + threadIdx.x;   // 0..NB-1
  float s = 0.f;
  for (int c = 0; c < NCT; ++c) s += partial[(size_t)c * NB + r];
  float li = logf(s) - out[(size_t)r * NC + targets[r]];
#pragma unroll
  for (int o = 32; o > 0; o >>= 1) li += __shfl_down(li, o);
  __shared__ float wsum[4];
  int lane = threadIdx.x & 63, wv = threadIdx.x >> 6;
  if (lane == 0) wsum[wv] = li;
  __syncthreads();
  if (threadIdx.x == 0) {
    float bs = wsum[0] + wsum[1] + wsum[2] + wsum[3];
    atomicAdd(loss, bs * (1.0f / NB));
  }
}

extern "C" void kernel_launch(void* const* d_in, const int* in_sizes, int n_in,
                              void* d_out, int out_size, void* d_ws, size_t ws_size,
                              hipStream_t stream) {
  const float* inputs  = (const float*)d_in[0];
  const int*   targets = (const int*)d_in[1];
  // d_in[2] indexs, d_in[3] label_to_pairs, d_in[4] all_label_to_clusterid: unused (W_MS = 0)
  const float* V       = (const float*)d_in[5];

  float* loss    = (float*)d_out;          // output 0: scalar loss
  float* outputs = (float*)d_out + 1;      // output 1: [4096][32000]

  char* ws = (char*)d_ws;
  unsigned short* Abf = (unsigned short*)ws;                              // 2 MB
  unsigned short* Vbf = (unsigned short*)(ws + (size_t)NB * ND * 2);      // 16.4 MB
  float* partial = (float*)(ws + (size_t)NB * ND * 2 + (size_t)NC * ND * 2); // 3.9 MB

  hipLaunchKernelGGL(prep_kernel, dim3(2048), dim3(256), 0, stream,
                     inputs, V, Abf, Vbf, loss);
  // grid: 8 XCDs x 1024 (32 col-tiles x 32 row-tiles), col-tiles padded to 256
  hipLaunchKernelGGL(gemm_expsum_kernel, dim3(8 * 1024), dim3(256), 0, stream,
                     Abf, Vbf, outputs, partial);
  hipLaunchKernelGGL(finalize_kernel, dim3(NB / 256), dim3(256), 0, stream,
                     partial, outputs, targets, loss);
}